// Round 4
// baseline (686.346 us; speedup 1.0000x reference)
//
#include <hip/hip_runtime.h>

#define NN 50000
#define NE 800000
#define DIM 64
#define TL 4
#define ET 3
#define MH 6
#define NBKT 3
#define NB (NN * NBKT)                  // 150000
#define SCAN_BLK ((NB + 1023) / 1024)   // 147

// ---------------- CSR build: 3 type buckets per node, hop packed in entry ----------------

static __global__ void k_hist3(const int* __restrict__ dst, const int* __restrict__ typ,
                               int* __restrict__ counts) {
    int e = blockIdx.x * blockDim.x + threadIdx.x;
    if (e >= NE) return;
    atomicAdd(&counts[dst[e] * NBKT + typ[e]], 1);
}

static __global__ void k_scanA(const int* __restrict__ counts, int* __restrict__ rs,
                               int* __restrict__ bsum) {
    __shared__ int sm[1024];
    int idx = blockIdx.x * 1024 + threadIdx.x;
    int v = (idx < NB) ? counts[idx] : 0;
    sm[threadIdx.x] = v;
    __syncthreads();
    for (int off = 1; off < 1024; off <<= 1) {
        int t = (threadIdx.x >= off) ? sm[threadIdx.x - off] : 0;
        __syncthreads();
        sm[threadIdx.x] += t;
        __syncthreads();
    }
    if (idx < NB) rs[idx] = sm[threadIdx.x] - v;   // exclusive within block
    if (threadIdx.x == 1023) bsum[blockIdx.x] = sm[1023];
}

static __global__ void k_scanB(const int* __restrict__ bsum, int* __restrict__ bexcl,
                               int* __restrict__ rs) {
    __shared__ int sm[512];
    int tid = threadIdx.x;
    int v = (tid < SCAN_BLK) ? bsum[tid] : 0;
    sm[tid] = v;
    __syncthreads();
    for (int off = 1; off < 512; off <<= 1) {
        int t = (tid >= off) ? sm[tid - off] : 0;
        __syncthreads();
        sm[tid] += t;
        __syncthreads();
    }
    if (tid < SCAN_BLK) bexcl[tid] = sm[tid] - v;
    if (tid == 511) rs[NB] = sm[511];              // grand total
}

static __global__ void k_scanC(int* __restrict__ rs, int* __restrict__ cursor,
                               const int* __restrict__ bexcl) {
    int idx = blockIdx.x * 1024 + threadIdx.x;
    if (idx >= NB) return;
    int r = rs[idx] + bexcl[blockIdx.x];
    rs[idx] = r;
    cursor[idx] = r;
}

static __global__ void k_scatter3(const int* __restrict__ src, const int* __restrict__ dst,
                                  const int* __restrict__ typ, const int* __restrict__ hop,
                                  int* __restrict__ cursor, unsigned int* __restrict__ src_s) {
    int e = blockIdx.x * blockDim.x + threadIdx.x;
    if (e >= NE) return;
    int slot = atomicAdd(&cursor[dst[e] * NBKT + typ[e]], 1);
    src_s[slot] = (unsigned int)src[e] | ((unsigned int)hop[e] << 16);
}

// ---------------- Aggregation: one wave per node, single merged loop ----------------

template <int T>
static __global__ __launch_bounds__(256) void k_agg(
        const int* __restrict__ rs, const unsigned int* __restrict__ src_s,
        const float* __restrict__ xt, const float* __restrict__ d2,
        const float* __restrict__ d3, const float* __restrict__ d4,
        const float* __restrict__ nu_edge, const float* __restrict__ nu_kt,
        float* __restrict__ aAll) {
    int g = blockIdx.x * blockDim.x + threadIdx.x;
    int node = g >> 6;
    if (node >= NN) return;
    int lane = g & 63;

    int ro = 0;
    if (lane < 4) ro = rs[node * NBKT + lane];
    const int b0 = __builtin_amdgcn_readlane(ro, 0);
    const int b1 = __builtin_amdgcn_readlane(ro, 1);
    const int b2 = __builtin_amdgcn_readlane(ro, 2);
    const int b3 = __builtin_amdgcn_readlane(ro, 3);   // == next node's b0 (contiguous)
    const int nt = b3 - b0, t1 = b1 - b0, t2 = b2 - b0;

    const float nk2 = (T >= 1) ? nu_kt[T * MH + 2] : 0.f;
    const float nk3 = (T >= 2) ? nu_kt[T * MH + 3] : 0.f;
    const float nk4 = (T >= 3) ? nu_kt[T * MH + 4] : 0.f;

    float s0 = 0.f, s1 = 0.f, s2 = 0.f, sH = 0.f;

    if (nt <= 64) {
        int sv = (lane < nt) ? (int)src_s[b0 + lane] : 0;
#pragma unroll 4
        for (int i = 0; i < nt; ++i) {
            unsigned int sp = (unsigned int)__builtin_amdgcn_readlane(sv, i);  // SGPR
            int srcn = (int)(sp & 0xFFFFu);
            int hop = (int)(sp >> 16);
            float v = xt[(size_t)srcn * DIM + lane];
            s0 = fmaf((i < t1) ? 1.f : 0.f, v, s0);
            s1 = fmaf((i >= t1 && i < t2) ? 1.f : 0.f, v, s1);
            s2 = fmaf((i >= t2) ? 1.f : 0.f, v, s2);
            if (T >= 1) {
                if (hop >= 2 && hop <= T + 1) {        // wave-uniform scalar branch
                    const float* hd = (hop == 2) ? d2 : (hop == 3) ? d3 : d4;
                    float sc = (hop == 2) ? nk2 : (hop == 3) ? nk3 : nk4;
                    sH = fmaf(sc, hd[(size_t)srcn * DIM + lane], sH);
                }
            }
        }
    } else {
        for (int i = 0; i < nt; ++i) {
            unsigned int sp = src_s[b0 + i];           // uniform address, broadcast
            int srcn = (int)(sp & 0xFFFFu);
            int hop = (int)(sp >> 16);
            float v = xt[(size_t)srcn * DIM + lane];
            s0 = fmaf((i < t1) ? 1.f : 0.f, v, s0);
            s1 = fmaf((i >= t1 && i < t2) ? 1.f : 0.f, v, s1);
            s2 = fmaf((i >= t2) ? 1.f : 0.f, v, s2);
            if (T >= 1) {
                if (hop >= 2 && hop <= T + 1) {
                    const float* hd = (hop == 2) ? d2 : (hop == 3) ? d3 : d4;
                    float sc = (hop == 2) ? nk2 : (hop == 3) ? nk3 : nk4;
                    sH = fmaf(sc, hd[(size_t)srcn * DIM + lane], sH);
                }
            }
        }
    }

    float nu0 = nu_edge[0 * TL + T], nu1 = nu_edge[1 * TL + T], nu2 = nu_edge[2 * TL + T];
    float* A = aAll + (size_t)node * (4 * DIM) + lane;
    A[0 * DIM] = nu0 * s0;
    A[1 * DIM] = nu1 * s1;
    A[2 * DIM] = nu2 * s2;
    A[3 * DIM] = sH;   // zeros at T=0 (unused by k_mm<0>)
}

// ---------------- Matmul: 16 nodes/wave, A via scalar loads, W coalesced ----------------

template <int T>
static __global__ __launch_bounds__(256) void k_mm(
        const float* __restrict__ aAll,
        const float* __restrict__ W_edge, const float* __restrict__ b_edge,
        const float* __restrict__ nu_edge,
        const float* __restrict__ W_t, const float* __restrict__ b_t,
        const float* __restrict__ nu_kt,
        const float* __restrict__ xin, float* __restrict__ xout) {
    const int wid = __builtin_amdgcn_readfirstlane(threadIdx.x >> 6);
    const int c = threadIdx.x & 63;
    const int node0 = blockIdx.x * 64 + wid * 16;
    if (node0 >= NN) return;   // NN % 16 == 0: active waves own 16 full nodes

    const float nu0 = nu_edge[0 * TL + T], nu1 = nu_edge[1 * TL + T],
                nu2 = nu_edge[2 * TL + T];
    float bias = nu0 * b_edge[(0 * TL + T) * DIM + c]
               + nu1 * b_edge[(1 * TL + T) * DIM + c]
               + nu2 * b_edge[(2 * TL + T) * DIM + c];
    if (T >= 1) {
        float ns = nu_kt[T * MH + 2];
        if (T >= 2) ns += nu_kt[T * MH + 3];
        if (T >= 3) ns += nu_kt[T * MH + 4];
        bias = fmaf(ns, b_t[T * DIM + c], bias);
    }

    float acc[16];
#pragma unroll
    for (int r = 0; r < 16; ++r) acc[r] = bias;

    constexpr int NM = (T >= 1) ? 4 : 3;
#pragma unroll
    for (int m = 0; m < NM; ++m) {
        const float* __restrict__ W = (m == 3) ? (W_t + (size_t)T * DIM * DIM)
                                               : (W_edge + (size_t)(m * TL + T) * DIM * DIM);
        const float* __restrict__ A = aAll + (size_t)node0 * (4 * DIM) + m * DIM;
        for (int d = 0; d < DIM; d += 4) {
            float w0 = W[(d + 0) * DIM + c];
            float w1 = W[(d + 1) * DIM + c];
            float w2 = W[(d + 2) * DIM + c];
            float w3 = W[(d + 3) * DIM + c];
#pragma unroll
            for (int r = 0; r < 16; ++r) {
                float4 av = *(const float4*)(A + (size_t)r * (4 * DIM) + d);  // uniform -> s_load
                acc[r] = fmaf(av.x, w0, acc[r]);
                acc[r] = fmaf(av.y, w1, acc[r]);
                acc[r] = fmaf(av.z, w2, acc[r]);
                acc[r] = fmaf(av.w, w3, acc[r]);
            }
        }
    }

#pragma unroll
    for (int r = 0; r < 16; ++r) {
        size_t idx = (size_t)(node0 + r) * DIM + c;
        float v = acc[r] > 0.f ? acc[r] : 0.f;
        xout[idx] = xin[idx] + v;
    }
}

// ---------------- Host ----------------

extern "C" void kernel_launch(void* const* d_in, const int* in_sizes, int n_in,
                              void* d_out, int out_size, void* d_ws, size_t ws_size,
                              hipStream_t stream) {
    const float* x       = (const float*)d_in[0];
    const float* W_edge  = (const float*)d_in[1];
    const float* b_edge  = (const float*)d_in[2];
    const float* nu_edge = (const float*)d_in[3];
    const float* W_t     = (const float*)d_in[4];
    const float* b_t     = (const float*)d_in[5];
    const float* nu_kt   = (const float*)d_in[6];
    const int* esrc = (const int*)d_in[7];
    const int* edst = (const int*)d_in[8];
    const int* ehop = (const int*)d_in[9];
    const int* etyp = (const int*)d_in[10];
    float* out = (float*)d_out;

    char* ws = (char*)d_ws;
    size_t off = 0;
    auto alloc = [&](size_t bytes) {
        void* p = ws + off;
        off = (off + bytes + 255) & ~(size_t)255;
        return p;
    };
    int* counts = (int*)alloc((size_t)NB * 4);
    int* rs     = (int*)alloc(((size_t)NB + 1) * 4);
    int* cursor = (int*)alloc((size_t)NB * 4);
    int* bsum   = (int*)alloc(1024 * 4);
    int* bexcl  = (int*)alloc(1024 * 4);
    unsigned int* src_s = (unsigned int*)alloc((size_t)NE * 4);
    float* h1   = (float*)alloc((size_t)NN * DIM * 4);
    float* h2   = (float*)alloc((size_t)NN * DIM * 4);
    float* h3   = (float*)alloc((size_t)NN * DIM * 4);
    float* aAll = (float*)alloc((size_t)NN * 4 * DIM * 4);
    (void)ws_size; (void)in_sizes; (void)n_in; (void)out_size;

    // CSR build (graph static across layers)
    hipMemsetAsync(counts, 0, (size_t)NB * 4, stream);
    k_hist3<<<(NE + 255) / 256, 256, 0, stream>>>(edst, etyp, counts);
    k_scanA<<<SCAN_BLK, 1024, 0, stream>>>(counts, rs, bsum);
    k_scanB<<<1, 512, 0, stream>>>(bsum, bexcl, rs);
    k_scanC<<<SCAN_BLK, 1024, 0, stream>>>(rs, cursor, bexcl);
    k_scatter3<<<(NE + 255) / 256, 256, 0, stream>>>(esrc, edst, etyp, ehop, cursor, src_s);

    const int ga = (NN * DIM + 255) / 256;   // one wave per node
    const int gm = (NN + 63) / 64;           // 16 nodes/wave, 4 waves/block

    // t = 0
    k_agg<0><<<ga, 256, 0, stream>>>(rs, src_s, x, x, x, x, nu_edge, nu_kt, aAll);
    k_mm<0><<<gm, 256, 0, stream>>>(aAll, W_edge, b_edge, nu_edge, W_t, b_t, nu_kt, x, h1);
    // t = 1: hop2 -> x
    k_agg<1><<<ga, 256, 0, stream>>>(rs, src_s, h1, x, x, x, nu_edge, nu_kt, aAll);
    k_mm<1><<<gm, 256, 0, stream>>>(aAll, W_edge, b_edge, nu_edge, W_t, b_t, nu_kt, h1, h2);
    // t = 2: hop2 -> h1, hop3 -> x
    k_agg<2><<<ga, 256, 0, stream>>>(rs, src_s, h2, h1, x, x, nu_edge, nu_kt, aAll);
    k_mm<2><<<gm, 256, 0, stream>>>(aAll, W_edge, b_edge, nu_edge, W_t, b_t, nu_kt, h2, h3);
    // t = 3: hop2 -> h2, hop3 -> h1, hop4 -> x
    k_agg<3><<<ga, 256, 0, stream>>>(rs, src_s, h3, h2, h1, x, nu_edge, nu_kt, aAll);
    k_mm<3><<<gm, 256, 0, stream>>>(aAll, W_edge, b_edge, nu_edge, W_t, b_t, nu_kt, h3, out);
}

// Round 5
// 604.423 us; speedup vs baseline: 1.1355x; 1.1355x over previous
//
#include <hip/hip_runtime.h>

#define NN 50000
#define NN_PAD 50048                    // 64-aligned, covers last k_mm tile
#define NE 800000
#define DIM 64
#define TL 4
#define ET 3
#define MH 6
#define NBKT 3
#define NB (NN * NBKT)                  // 150000
#define SCAN_BLK ((NB + 1023) / 1024)   // 147

// ---------------- CSR build: 3 type buckets per node, hop packed in entry ----------------

static __global__ void k_hist3(const int* __restrict__ dst, const int* __restrict__ typ,
                               int* __restrict__ counts) {
    int e = blockIdx.x * blockDim.x + threadIdx.x;
    if (e >= NE) return;
    atomicAdd(&counts[dst[e] * NBKT + typ[e]], 1);
}

static __global__ void k_scanA(const int* __restrict__ counts, int* __restrict__ rs,
                               int* __restrict__ bsum) {
    __shared__ int sm[1024];
    int idx = blockIdx.x * 1024 + threadIdx.x;
    int v = (idx < NB) ? counts[idx] : 0;
    sm[threadIdx.x] = v;
    __syncthreads();
    for (int off = 1; off < 1024; off <<= 1) {
        int t = (threadIdx.x >= off) ? sm[threadIdx.x - off] : 0;
        __syncthreads();
        sm[threadIdx.x] += t;
        __syncthreads();
    }
    if (idx < NB) rs[idx] = sm[threadIdx.x] - v;   // exclusive within block
    if (threadIdx.x == 1023) bsum[blockIdx.x] = sm[1023];
}

static __global__ void k_scanB(const int* __restrict__ bsum, int* __restrict__ bexcl,
                               int* __restrict__ rs) {
    __shared__ int sm[512];
    int tid = threadIdx.x;
    int v = (tid < SCAN_BLK) ? bsum[tid] : 0;
    sm[tid] = v;
    __syncthreads();
    for (int off = 1; off < 512; off <<= 1) {
        int t = (tid >= off) ? sm[tid - off] : 0;
        __syncthreads();
        sm[tid] += t;
        __syncthreads();
    }
    if (tid < SCAN_BLK) bexcl[tid] = sm[tid] - v;
    if (tid == 511) rs[NB] = sm[511];              // grand total
}

static __global__ void k_scanC(int* __restrict__ rs, int* __restrict__ cursor,
                               const int* __restrict__ bexcl) {
    int idx = blockIdx.x * 1024 + threadIdx.x;
    if (idx >= NB) return;
    int r = rs[idx] + bexcl[blockIdx.x];
    rs[idx] = r;
    cursor[idx] = r;
}

static __global__ void k_scatter3(const int* __restrict__ src, const int* __restrict__ dst,
                                  const int* __restrict__ typ, const int* __restrict__ hop,
                                  int* __restrict__ cursor, unsigned int* __restrict__ src_s) {
    int e = blockIdx.x * blockDim.x + threadIdx.x;
    if (e >= NE) return;
    int slot = atomicAdd(&cursor[dst[e] * NBKT + typ[e]], 1);
    src_s[slot] = (unsigned int)src[e] | ((unsigned int)hop[e] << 16);
}

// ---------------- Aggregation: one wave per node, branchless hop gather ----------------

template <int T>
static __global__ __launch_bounds__(256) void k_agg(
        const int* __restrict__ rs, const unsigned int* __restrict__ src_s,
        const float* __restrict__ xt, const float* __restrict__ d2,
        const float* __restrict__ d3, const float* __restrict__ d4,
        const float* __restrict__ nu_edge, const float* __restrict__ nu_kt,
        float* __restrict__ aAll) {
    int g = blockIdx.x * blockDim.x + threadIdx.x;
    int node = g >> 6;
    if (node >= NN) return;
    int lane = g & 63;

    int ro = 0;
    if (lane < 4) ro = rs[node * NBKT + lane];
    const int b0 = __builtin_amdgcn_readlane(ro, 0);
    const int b1 = __builtin_amdgcn_readlane(ro, 1);
    const int b2 = __builtin_amdgcn_readlane(ro, 2);
    const int b3 = __builtin_amdgcn_readlane(ro, 3);
    const int nt = b3 - b0, t1 = b1 - b0, t2 = b2 - b0;

    const float nk2 = (T >= 1) ? nu_kt[T * MH + 2] : 0.f;
    const float nk3 = (T >= 2) ? nu_kt[T * MH + 3] : 0.f;
    const float nk4 = (T >= 3) ? nu_kt[T * MH + 4] : 0.f;

    float s0 = 0.f, s1 = 0.f, s2 = 0.f, sH = 0.f;

    if (nt <= 64) {
        int sv = (lane < nt) ? (int)src_s[b0 + lane] : 0;
#pragma unroll 4
        for (int i = 0; i < nt; ++i) {
            unsigned int sp = (unsigned int)__builtin_amdgcn_readlane(sv, i);  // SGPR
            int srcn = (int)(sp & 0xFFFFu);
            int hop = (int)(sp >> 16);
            float v = xt[(size_t)srcn * DIM + lane];
            s0 = fmaf((i < t1) ? 1.f : 0.f, v, s0);
            s1 = fmaf((i >= t1 && i < t2) ? 1.f : 0.f, v, s1);
            s2 = fmaf((i >= t2) ? 1.f : 0.f, v, s2);
            if (T >= 1) {
                // invalid hops point at xt (row just loaded -> L1 hit) with scale 0
                const float* hd = (hop == 2) ? d2
                                 : (hop == 3 && T >= 2) ? d3
                                 : (hop == 4 && T >= 3) ? d4 : xt;
                float sc = (hop == 2) ? nk2
                          : (hop == 3 && T >= 2) ? nk3
                          : (hop == 4 && T >= 3) ? nk4 : 0.f;
                sH = fmaf(sc, hd[(size_t)srcn * DIM + lane], sH);
            }
        }
    } else {
        for (int i = 0; i < nt; ++i) {
            unsigned int sp = src_s[b0 + i];           // uniform address, broadcast
            int srcn = (int)(sp & 0xFFFFu);
            int hop = (int)(sp >> 16);
            float v = xt[(size_t)srcn * DIM + lane];
            s0 = fmaf((i < t1) ? 1.f : 0.f, v, s0);
            s1 = fmaf((i >= t1 && i < t2) ? 1.f : 0.f, v, s1);
            s2 = fmaf((i >= t2) ? 1.f : 0.f, v, s2);
            if (T >= 1) {
                const float* hd = (hop == 2) ? d2
                                 : (hop == 3 && T >= 2) ? d3
                                 : (hop == 4 && T >= 3) ? d4 : xt;
                float sc = (hop == 2) ? nk2
                          : (hop == 3 && T >= 2) ? nk3
                          : (hop == 4 && T >= 3) ? nk4 : 0.f;
                sH = fmaf(sc, hd[(size_t)srcn * DIM + lane], sH);
            }
        }
    }

    float nu0 = nu_edge[0 * TL + T], nu1 = nu_edge[1 * TL + T], nu2 = nu_edge[2 * TL + T];
    float* A = aAll + (size_t)node * DIM + lane;
    A[(size_t)0 * NN_PAD * DIM] = nu0 * s0;
    A[(size_t)1 * NN_PAD * DIM] = nu1 * s1;
    A[(size_t)2 * NN_PAD * DIM] = nu2 * s2;
    if (T >= 1) A[(size_t)3 * NN_PAD * DIM] = sH;
}

// ---------------- Matmul: 512 thr / 64 nodes per block, A-tile in LDS ----------------

template <int T>
static __global__ __launch_bounds__(512) void k_mm(
        const float* __restrict__ aAll,
        const float* __restrict__ W_edge, const float* __restrict__ b_edge,
        const float* __restrict__ nu_edge,
        const float* __restrict__ W_t, const float* __restrict__ b_t,
        const float* __restrict__ nu_kt,
        const float* __restrict__ xin, float* __restrict__ xout) {
    __shared__ float Asm[64 * DIM];    // 16 KB: [node-in-tile][64]
    const int tid = threadIdx.x;
    const int w = tid >> 6;            // wave 0..7 -> nodes w*8..w*8+7
    const int c = tid & 63;
    const int node0 = blockIdx.x * 64;

    const float nu0 = nu_edge[0 * TL + T], nu1 = nu_edge[1 * TL + T],
                nu2 = nu_edge[2 * TL + T];
    float bias = nu0 * b_edge[(0 * TL + T) * DIM + c]
               + nu1 * b_edge[(1 * TL + T) * DIM + c]
               + nu2 * b_edge[(2 * TL + T) * DIM + c];
    if (T >= 1) {
        float ns = nu_kt[T * MH + 2];
        if (T >= 2) ns += nu_kt[T * MH + 3];
        if (T >= 3) ns += nu_kt[T * MH + 4];
        bias = fmaf(ns, b_t[T * DIM + c], bias);
    }

    float acc[8];
#pragma unroll
    for (int r = 0; r < 8; ++r) acc[r] = bias;

    constexpr int NM = (T >= 1) ? 4 : 3;
#pragma unroll 1
    for (int m = 0; m < NM; ++m) {
        __syncthreads();
        // stage A-tile for matrix m: 64 nodes x 64 floats = 1024 float4
        const float4* s4 = (const float4*)(aAll + ((size_t)m * NN_PAD + node0) * DIM);
        float4* d4p = (float4*)Asm;
        d4p[tid] = s4[tid];
        d4p[tid + 512] = s4[tid + 512];
        __syncthreads();

        const float* __restrict__ W = (m == 3) ? (W_t + (size_t)T * DIM * DIM)
                                               : (W_edge + (size_t)(m * TL + T) * DIM * DIM);
        const int abase = w * 8 * DIM;
#pragma unroll 4
        for (int d = 0; d < DIM; d += 4) {
            float w0 = W[(d + 0) * DIM + c];
            float w1 = W[(d + 1) * DIM + c];
            float w2 = W[(d + 2) * DIM + c];
            float w3 = W[(d + 3) * DIM + c];
#pragma unroll
            for (int r = 0; r < 8; ++r) {
                float4 av = *(const float4*)(&Asm[abase + r * DIM + d]);  // uniform broadcast
                acc[r] = fmaf(av.x, w0, acc[r]);
                acc[r] = fmaf(av.y, w1, acc[r]);
                acc[r] = fmaf(av.z, w2, acc[r]);
                acc[r] = fmaf(av.w, w3, acc[r]);
            }
        }
    }

#pragma unroll
    for (int r = 0; r < 8; ++r) {
        int n = node0 + w * 8 + r;
        if (n < NN) {
            size_t idx = (size_t)n * DIM + c;
            float v = acc[r] > 0.f ? acc[r] : 0.f;
            xout[idx] = xin[idx] + v;
        }
    }
}

// ---------------- Host ----------------

extern "C" void kernel_launch(void* const* d_in, const int* in_sizes, int n_in,
                              void* d_out, int out_size, void* d_ws, size_t ws_size,
                              hipStream_t stream) {
    const float* x       = (const float*)d_in[0];
    const float* W_edge  = (const float*)d_in[1];
    const float* b_edge  = (const float*)d_in[2];
    const float* nu_edge = (const float*)d_in[3];
    const float* W_t     = (const float*)d_in[4];
    const float* b_t     = (const float*)d_in[5];
    const float* nu_kt   = (const float*)d_in[6];
    const int* esrc = (const int*)d_in[7];
    const int* edst = (const int*)d_in[8];
    const int* ehop = (const int*)d_in[9];
    const int* etyp = (const int*)d_in[10];
    float* out = (float*)d_out;

    char* ws = (char*)d_ws;
    size_t off = 0;
    auto alloc = [&](size_t bytes) {
        void* p = ws + off;
        off = (off + bytes + 255) & ~(size_t)255;
        return p;
    };
    int* counts = (int*)alloc((size_t)NB * 4);
    int* rs     = (int*)alloc(((size_t)NB + 1) * 4);
    int* cursor = (int*)alloc((size_t)NB * 4);
    int* bsum   = (int*)alloc(1024 * 4);
    int* bexcl  = (int*)alloc(1024 * 4);
    unsigned int* src_s = (unsigned int*)alloc((size_t)NE * 4);
    float* h1   = (float*)alloc((size_t)NN * DIM * 4);
    float* h2   = (float*)alloc((size_t)NN * DIM * 4);
    float* h3   = (float*)alloc((size_t)NN * DIM * 4);
    float* aAll = (float*)alloc((size_t)4 * NN_PAD * DIM * 4);   // mat-major [4][NN_PAD][64]
    (void)ws_size; (void)in_sizes; (void)n_in; (void)out_size;

    // CSR build (graph static across layers)
    hipMemsetAsync(counts, 0, (size_t)NB * 4, stream);
    k_hist3<<<(NE + 255) / 256, 256, 0, stream>>>(edst, etyp, counts);
    k_scanA<<<SCAN_BLK, 1024, 0, stream>>>(counts, rs, bsum);
    k_scanB<<<1, 512, 0, stream>>>(bsum, bexcl, rs);
    k_scanC<<<SCAN_BLK, 1024, 0, stream>>>(rs, cursor, bexcl);
    k_scatter3<<<(NE + 255) / 256, 256, 0, stream>>>(esrc, edst, etyp, ehop, cursor, src_s);

    const int ga = (NN * DIM + 255) / 256;   // one wave per node
    const int gm = (NN + 63) / 64;           // 64 nodes per 512-thread block

    // t = 0
    k_agg<0><<<ga, 256, 0, stream>>>(rs, src_s, x, x, x, x, nu_edge, nu_kt, aAll);
    k_mm<0><<<gm, 512, 0, stream>>>(aAll, W_edge, b_edge, nu_edge, W_t, b_t, nu_kt, x, h1);
    // t = 1: hop2 -> x
    k_agg<1><<<ga, 256, 0, stream>>>(rs, src_s, h1, x, x, x, nu_edge, nu_kt, aAll);
    k_mm<1><<<gm, 512, 0, stream>>>(aAll, W_edge, b_edge, nu_edge, W_t, b_t, nu_kt, h1, h2);
    // t = 2: hop2 -> h1, hop3 -> x
    k_agg<2><<<ga, 256, 0, stream>>>(rs, src_s, h2, h1, x, x, nu_edge, nu_kt, aAll);
    k_mm<2><<<gm, 512, 0, stream>>>(aAll, W_edge, b_edge, nu_edge, W_t, b_t, nu_kt, h2, h3);
    // t = 3: hop2 -> h2, hop3 -> h1, hop4 -> x
    k_agg<3><<<ga, 256, 0, stream>>>(rs, src_s, h3, h2, h1, x, nu_edge, nu_kt, aAll);
    k_mm<3><<<gm, 512, 0, stream>>>(aAll, W_edge, b_edge, nu_edge, W_t, b_t, nu_kt, h3, out);
}

// Round 6
// 484.163 us; speedup vs baseline: 1.4176x; 1.2484x over previous
//
#include <hip/hip_runtime.h>

#define NN 50000
#define NN_PAD 50048                    // 64-aligned, covers last k_mm tile
#define NE 800000
#define DIM 64
#define TL 4
#define ET 3
#define MH 6
#define NBKT 3
#define NB (NN * NBKT)                  // 150000
#define SCAN_BLK ((NB + 1023) / 1024)   // 147

// ---------------- CSR build: 3 type buckets per node, hop packed in entry ----------------

static __global__ void k_hist3(const int* __restrict__ dst, const int* __restrict__ typ,
                               int* __restrict__ counts) {
    int e = blockIdx.x * blockDim.x + threadIdx.x;
    if (e >= NE) return;
    atomicAdd(&counts[dst[e] * NBKT + typ[e]], 1);
}

static __global__ void k_scanA(const int* __restrict__ counts, int* __restrict__ rs,
                               int* __restrict__ bsum) {
    __shared__ int sm[1024];
    int idx = blockIdx.x * 1024 + threadIdx.x;
    int v = (idx < NB) ? counts[idx] : 0;
    sm[threadIdx.x] = v;
    __syncthreads();
    for (int off = 1; off < 1024; off <<= 1) {
        int t = (threadIdx.x >= off) ? sm[threadIdx.x - off] : 0;
        __syncthreads();
        sm[threadIdx.x] += t;
        __syncthreads();
    }
    if (idx < NB) rs[idx] = sm[threadIdx.x] - v;   // exclusive within block
    if (threadIdx.x == 1023) bsum[blockIdx.x] = sm[1023];
}

static __global__ void k_scanB(const int* __restrict__ bsum, int* __restrict__ bexcl,
                               int* __restrict__ rs) {
    __shared__ int sm[512];
    int tid = threadIdx.x;
    int v = (tid < SCAN_BLK) ? bsum[tid] : 0;
    sm[tid] = v;
    __syncthreads();
    for (int off = 1; off < 512; off <<= 1) {
        int t = (tid >= off) ? sm[tid - off] : 0;
        __syncthreads();
        sm[tid] += t;
        __syncthreads();
    }
    if (tid < SCAN_BLK) bexcl[tid] = sm[tid] - v;
    if (tid == 511) rs[NB] = sm[511];              // grand total
}

static __global__ void k_scanC(int* __restrict__ rs, int* __restrict__ cursor,
                               const int* __restrict__ bexcl) {
    int idx = blockIdx.x * 1024 + threadIdx.x;
    if (idx >= NB) return;
    int r = rs[idx] + bexcl[blockIdx.x];
    rs[idx] = r;
    cursor[idx] = r;
}

static __global__ void k_scatter3(const int* __restrict__ src, const int* __restrict__ dst,
                                  const int* __restrict__ typ, const int* __restrict__ hop,
                                  int* __restrict__ cursor, unsigned int* __restrict__ src_s) {
    int e = blockIdx.x * blockDim.x + threadIdx.x;
    if (e >= NE) return;
    int slot = atomicAdd(&cursor[dst[e] * NBKT + typ[e]], 1);
    src_s[slot] = (unsigned int)src[e] | ((unsigned int)hop[e] << 16);
}

// ---------------- Aggregation: one wave per node, branchless hop gather ----------------

template <int T>
static __global__ __launch_bounds__(256) void k_agg(
        const int* __restrict__ rs, const unsigned int* __restrict__ src_s,
        const float* __restrict__ xt, const float* __restrict__ d2,
        const float* __restrict__ d3, const float* __restrict__ d4,
        const float* __restrict__ nu_edge, const float* __restrict__ nu_kt,
        float* __restrict__ aAll) {
    int g = blockIdx.x * blockDim.x + threadIdx.x;
    int node = g >> 6;
    if (node >= NN) return;
    int lane = g & 63;

    int ro = 0;
    if (lane < 4) ro = rs[node * NBKT + lane];
    const int b0 = __builtin_amdgcn_readlane(ro, 0);
    const int b1 = __builtin_amdgcn_readlane(ro, 1);
    const int b2 = __builtin_amdgcn_readlane(ro, 2);
    const int b3 = __builtin_amdgcn_readlane(ro, 3);
    const int nt = b3 - b0, t1 = b1 - b0, t2 = b2 - b0;

    const float nk2 = (T >= 1) ? nu_kt[T * MH + 2] : 0.f;
    const float nk3 = (T >= 2) ? nu_kt[T * MH + 3] : 0.f;
    const float nk4 = (T >= 3) ? nu_kt[T * MH + 4] : 0.f;

    float s0 = 0.f, s1 = 0.f, s2 = 0.f, sH = 0.f;

    if (nt <= 64) {
        int sv = (lane < nt) ? (int)src_s[b0 + lane] : 0;
#pragma unroll 4
        for (int i = 0; i < nt; ++i) {
            unsigned int sp = (unsigned int)__builtin_amdgcn_readlane(sv, i);  // SGPR
            int srcn = (int)(sp & 0xFFFFu);
            int hop = (int)(sp >> 16);
            float v = xt[(size_t)srcn * DIM + lane];
            s0 = fmaf((i < t1) ? 1.f : 0.f, v, s0);
            s1 = fmaf((i >= t1 && i < t2) ? 1.f : 0.f, v, s1);
            s2 = fmaf((i >= t2) ? 1.f : 0.f, v, s2);
            if (T >= 1) {
                // invalid hops point at xt (row just loaded -> L1 hit) with scale 0
                const float* hd = (hop == 2) ? d2
                                 : (hop == 3 && T >= 2) ? d3
                                 : (hop == 4 && T >= 3) ? d4 : xt;
                float sc = (hop == 2) ? nk2
                          : (hop == 3 && T >= 2) ? nk3
                          : (hop == 4 && T >= 3) ? nk4 : 0.f;
                sH = fmaf(sc, hd[(size_t)srcn * DIM + lane], sH);
            }
        }
    } else {
        for (int i = 0; i < nt; ++i) {
            unsigned int sp = src_s[b0 + i];           // uniform address, broadcast
            int srcn = (int)(sp & 0xFFFFu);
            int hop = (int)(sp >> 16);
            float v = xt[(size_t)srcn * DIM + lane];
            s0 = fmaf((i < t1) ? 1.f : 0.f, v, s0);
            s1 = fmaf((i >= t1 && i < t2) ? 1.f : 0.f, v, s1);
            s2 = fmaf((i >= t2) ? 1.f : 0.f, v, s2);
            if (T >= 1) {
                const float* hd = (hop == 2) ? d2
                                 : (hop == 3 && T >= 2) ? d3
                                 : (hop == 4 && T >= 3) ? d4 : xt;
                float sc = (hop == 2) ? nk2
                          : (hop == 3 && T >= 2) ? nk3
                          : (hop == 4 && T >= 3) ? nk4 : 0.f;
                sH = fmaf(sc, hd[(size_t)srcn * DIM + lane], sH);
            }
        }
    }

    float nu0 = nu_edge[0 * TL + T], nu1 = nu_edge[1 * TL + T], nu2 = nu_edge[2 * TL + T];
    float* A = aAll + (size_t)node * DIM + lane;
    A[(size_t)0 * NN_PAD * DIM] = nu0 * s0;
    A[(size_t)1 * NN_PAD * DIM] = nu1 * s1;
    A[(size_t)2 * NN_PAD * DIM] = nu2 * s2;
    if (T >= 1) A[(size_t)3 * NN_PAD * DIM] = sH;
}

// ---------------- Matmul: lane = node, W via wave-uniform scalar loads ----------------
// Block = 256 thr = 4 waves over a 64-node tile; wave w -> cols [16w, 16w+16).
// No LDS, no barriers. FMA = v_fmac(acc_v, W_s, a_v): VALU-bound by design.

template <int T>
static __global__ __launch_bounds__(256) void k_mm(
        const float* __restrict__ aAll,
        const float* __restrict__ W_edge, const float* __restrict__ b_edge,
        const float* __restrict__ nu_edge,
        const float* __restrict__ W_t, const float* __restrict__ b_t,
        const float* __restrict__ nu_kt,
        const float* __restrict__ xin, float* __restrict__ xout) {
    const int w = __builtin_amdgcn_readfirstlane(threadIdx.x >> 6);  // uniform wave id
    const int lane = threadIdx.x & 63;
    const int node = blockIdx.x * 64 + lane;     // lane = node within tile
    const int c0 = w * 16;

    const float nu0 = nu_edge[0 * TL + T], nu1 = nu_edge[1 * TL + T],
                nu2 = nu_edge[2 * TL + T];
    float nsum = 0.f;
    if (T >= 1) {
        nsum = nu_kt[T * MH + 2];
        if (T >= 2) nsum += nu_kt[T * MH + 3];
        if (T >= 3) nsum += nu_kt[T * MH + 4];
    }

    float acc[16];
#pragma unroll
    for (int c = 0; c < 16; ++c) {
        float b = nu0 * b_edge[(0 * TL + T) * DIM + c0 + c]
                + nu1 * b_edge[(1 * TL + T) * DIM + c0 + c]
                + nu2 * b_edge[(2 * TL + T) * DIM + c0 + c];
        if (T >= 1) b = fmaf(nsum, b_t[T * DIM + c0 + c], b);
        acc[c] = b;                                  // uniform -> SGPR-computed, splat once
    }

    constexpr int NM = (T >= 1) ? 4 : 3;
#pragma unroll
    for (int m = 0; m < NM; ++m) {
        const float* __restrict__ W = (m == 3) ? (W_t + (size_t)T * DIM * DIM)
                                               : (W_edge + (size_t)(m * TL + T) * DIM * DIM);
        // per-lane A row (this node, matrix m): 16 independent float4 loads
        const float4* __restrict__ A4 =
            (const float4*)(aAll + ((size_t)m * NN_PAD + (size_t)blockIdx.x * 64 + lane) * DIM);
#pragma unroll 4
        for (int dg = 0; dg < 16; ++dg) {
            float4 av = A4[dg];
#pragma unroll
            for (int jd = 0; jd < 4; ++jd) {
                const float* __restrict__ Wr = W + (dg * 4 + jd) * DIM + c0;  // wave-uniform
                float a = (jd == 0) ? av.x : (jd == 1) ? av.y : (jd == 2) ? av.z : av.w;
#pragma unroll
                for (int c = 0; c < 16; ++c)
                    acc[c] = fmaf(a, Wr[c], acc[c]);   // s_load W + v_fmac
            }
        }
    }

    if (node < NN) {
        const float4* __restrict__ X4 = (const float4*)(xin + (size_t)node * DIM + c0);
        float4* __restrict__ O4 = (float4*)(xout + (size_t)node * DIM + c0);
#pragma unroll
        for (int q = 0; q < 4; ++q) {
            float4 xv = X4[q];
            float4 ov;
            ov.x = xv.x + fmaxf(acc[q * 4 + 0], 0.f);
            ov.y = xv.y + fmaxf(acc[q * 4 + 1], 0.f);
            ov.z = xv.z + fmaxf(acc[q * 4 + 2], 0.f);
            ov.w = xv.w + fmaxf(acc[q * 4 + 3], 0.f);
            O4[q] = ov;
        }
    }
}

// ---------------- Host ----------------

extern "C" void kernel_launch(void* const* d_in, const int* in_sizes, int n_in,
                              void* d_out, int out_size, void* d_ws, size_t ws_size,
                              hipStream_t stream) {
    const float* x       = (const float*)d_in[0];
    const float* W_edge  = (const float*)d_in[1];
    const float* b_edge  = (const float*)d_in[2];
    const float* nu_edge = (const float*)d_in[3];
    const float* W_t     = (const float*)d_in[4];
    const float* b_t     = (const float*)d_in[5];
    const float* nu_kt   = (const float*)d_in[6];
    const int* esrc = (const int*)d_in[7];
    const int* edst = (const int*)d_in[8];
    const int* ehop = (const int*)d_in[9];
    const int* etyp = (const int*)d_in[10];
    float* out = (float*)d_out;

    char* ws = (char*)d_ws;
    size_t off = 0;
    auto alloc = [&](size_t bytes) {
        void* p = ws + off;
        off = (off + bytes + 255) & ~(size_t)255;
        return p;
    };
    int* counts = (int*)alloc((size_t)NB * 4);
    int* rs     = (int*)alloc(((size_t)NB + 1) * 4);
    int* cursor = (int*)alloc((size_t)NB * 4);
    int* bsum   = (int*)alloc(1024 * 4);
    int* bexcl  = (int*)alloc(1024 * 4);
    unsigned int* src_s = (unsigned int*)alloc((size_t)NE * 4);
    float* h1   = (float*)alloc((size_t)NN * DIM * 4);
    float* h2   = (float*)alloc((size_t)NN * DIM * 4);
    float* h3   = (float*)alloc((size_t)NN * DIM * 4);
    float* aAll = (float*)alloc((size_t)4 * NN_PAD * DIM * 4);   // mat-major [4][NN_PAD][64]
    (void)ws_size; (void)in_sizes; (void)n_in; (void)out_size;

    // CSR build (graph static across layers)
    hipMemsetAsync(counts, 0, (size_t)NB * 4, stream);
    k_hist3<<<(NE + 255) / 256, 256, 0, stream>>>(edst, etyp, counts);
    k_scanA<<<SCAN_BLK, 1024, 0, stream>>>(counts, rs, bsum);
    k_scanB<<<1, 512, 0, stream>>>(bsum, bexcl, rs);
    k_scanC<<<SCAN_BLK, 1024, 0, stream>>>(rs, cursor, bexcl);
    k_scatter3<<<(NE + 255) / 256, 256, 0, stream>>>(esrc, edst, etyp, ehop, cursor, src_s);

    const int ga = (NN * DIM + 255) / 256;   // one wave per node
    const int gm = NN_PAD / 64;              // 782 blocks, 64-node tile each

    // t = 0
    k_agg<0><<<ga, 256, 0, stream>>>(rs, src_s, x, x, x, x, nu_edge, nu_kt, aAll);
    k_mm<0><<<gm, 256, 0, stream>>>(aAll, W_edge, b_edge, nu_edge, W_t, b_t, nu_kt, x, h1);
    // t = 1: hop2 -> x
    k_agg<1><<<ga, 256, 0, stream>>>(rs, src_s, h1, x, x, x, nu_edge, nu_kt, aAll);
    k_mm<1><<<gm, 256, 0, stream>>>(aAll, W_edge, b_edge, nu_edge, W_t, b_t, nu_kt, h1, h2);
    // t = 2: hop2 -> h1, hop3 -> x
    k_agg<2><<<ga, 256, 0, stream>>>(rs, src_s, h2, h1, x, x, nu_edge, nu_kt, aAll);
    k_mm<2><<<gm, 256, 0, stream>>>(aAll, W_edge, b_edge, nu_edge, W_t, b_t, nu_kt, h2, h3);
    // t = 3: hop2 -> h2, hop3 -> h1, hop4 -> x
    k_agg<3><<<ga, 256, 0, stream>>>(rs, src_s, h3, h2, h1, x, nu_edge, nu_kt, aAll);
    k_mm<3><<<gm, 256, 0, stream>>>(aAll, W_edge, b_edge, nu_edge, W_t, b_t, nu_kt, h3, out);
}